// Round 2
// baseline (1711.716 us; speedup 1.0000x reference)
//
#include <hip/hip_runtime.h>
#include <hip/hip_bf16.h>
#include <cstddef>
#include <cstdint>

#define N_NODES 10000
#define N_EDGES 160000
#define BATCH 32
#define IN_FEAT 64
#define POLY_K 5
#define OUT_FEAT 128
#define KTOT 320               // IN_FEAT * POLY_K
#define POOLSZ 4
#define NPOOL 2500

// ---------------- CSR build ----------------

__global__ void zero_int_kernel(int* __restrict__ p, int n) {
  int i = blockIdx.x * 256 + threadIdx.x;
  if (i < n) p[i] = 0;
}

__global__ void hist_kernel(const int* __restrict__ rows, int* __restrict__ deg) {
  int e = blockIdx.x * 256 + threadIdx.x;
  if (e < N_EDGES) atomicAdd(&deg[rows[e]], 1);
}

__global__ void scan_kernel(const int* __restrict__ deg, int* __restrict__ row_start,
                            int* __restrict__ cursor) {
  __shared__ int sm[1024];
  __shared__ int carry;
  int t = threadIdx.x;
  if (t == 0) { carry = 0; row_start[0] = 0; }
  __syncthreads();
  for (int base = 0; base < N_NODES; base += 1024) {
    int idx = base + t;
    int v = (idx < N_NODES) ? deg[idx] : 0;
    sm[t] = v;
    __syncthreads();
    for (int off = 1; off < 1024; off <<= 1) {
      int xv = 0;
      if (t >= off) xv = sm[t - off];
      __syncthreads();
      sm[t] += xv;
      __syncthreads();
    }
    if (idx < N_NODES) {
      int incl = sm[t];
      row_start[idx + 1] = carry + incl;
      cursor[idx] = carry + incl - v;
    }
    __syncthreads();
    if (t == 1023) carry += sm[1023];
    __syncthreads();
  }
}

__global__ void scatter_kernel(const int* __restrict__ rows, const int* __restrict__ cols,
                               const float* __restrict__ vals, int* __restrict__ cursor,
                               int* __restrict__ csr_cols, float* __restrict__ csr_vals) {
  int e = blockIdx.x * 256 + threadIdx.x;
  if (e < N_EDGES) {
    int r = rows[e];
    int p = atomicAdd(&cursor[r], 1);
    csr_cols[p] = cols[e];
    csr_vals[p] = vals[e];
  }
}

// ---------------- transpose: slice0[n][b*64+f] = x[b0+b][n][f] ----------------

template <int BB>
__global__ void transpose_kernel(const float* __restrict__ x, float* __restrict__ t0, int b0) {
  constexpr int CB = 64 * BB;
  int n = blockIdx.x;
  int t = threadIdx.x;
  #pragma unroll
  for (int i = t * 4; i < CB; i += 256) {
    int b = i >> 6;
    float4 v = *(const float4*)&x[((size_t)(b0 + b) * N_NODES + n) * IN_FEAT + (i & 63)];
    *(float4*)&t0[(size_t)n * CB + i] = v;
  }
}

// ---------------- SpMM: xout[n,:] = alpha * sum val*xin[col,:] (- prev[n,:]) ----------------

template <int BB>
__global__ void spmm_kernel(const float* __restrict__ xin, const float* __restrict__ prev,
                            float* __restrict__ xout,
                            const int* __restrict__ row_start,
                            const int* __restrict__ csr_cols, const float* __restrict__ csr_vals,
                            float alpha, int use_prev) {
  constexpr int CB = 64 * BB;
  constexpr int NV = (CB + 255) / 256;   // float4 slots per thread (64 threads)
  int n = blockIdx.x;
  int t = threadIdx.x;
  int s = row_start[n];
  int e = row_start[n + 1];
  float4 acc[NV];
  #pragma unroll
  for (int j = 0; j < NV; ++j) acc[j] = make_float4(0.f, 0.f, 0.f, 0.f);
  for (int i = s; i < e; ++i) {
    int col = csr_cols[i];
    float v = csr_vals[i];
    const float* src = xin + (size_t)col * CB;
    #pragma unroll
    for (int j = 0; j < NV; ++j) {
      int c = t * 4 + j * 256;
      if (c < CB) {
        float4 p = *(const float4*)(src + c);
        acc[j].x += v * p.x; acc[j].y += v * p.y;
        acc[j].z += v * p.z; acc[j].w += v * p.w;
      }
    }
  }
  #pragma unroll
  for (int j = 0; j < NV; ++j) {
    int c = t * 4 + j * 256;
    if (c < CB) {
      float4 r;
      r.x = alpha * acc[j].x; r.y = alpha * acc[j].y;
      r.z = alpha * acc[j].z; r.w = alpha * acc[j].w;
      if (use_prev) {
        float4 q = *(const float4*)(prev + (size_t)n * CB + c);
        r.x -= q.x; r.y -= q.y; r.z -= q.z; r.w -= q.w;
      }
      *(float4*)(xout + (size_t)n * CB + c) = r;
    }
  }
}

// ---------------- fused GEMM + bias + ReLU + maxpool(4) for one batch-block ----------------
// out[b0+b, g, fo] = max_{nd} relu( sum_{f,k} T_k[g*4+nd][b*64+f] * W[f*5+k][fo] + bias[fo] )

#define KC 40   // K-chunk of W staged in LDS (40*128*4 = 20 KB)

template <int BB>
__global__ __launch_bounds__(256) void gemm_kernel(const float* __restrict__ slices,
                                                   const float* __restrict__ weight,
                                                   const float* __restrict__ bias,
                                                   float* __restrict__ out, int b0) {
  constexpr int CB = 64 * BB;
  constexpr int BTILE = (BB >= 4) ? 4 : BB;   // b per thread
  constexpr int NBG = BB / BTILE;             // 2 for BB=8, else 1
  constexpr int TPG = NBG * 32;               // threads per pooled-group
  constexpr int PG = 256 / TPG;               // pooled groups per block
  constexpr size_t SLICE = (size_t)N_NODES * CB;

  __shared__ float As[PG][KTOT * BB];         // [pg][kidx*BB + b]
  __shared__ float Ws[KC * OUT_FEAT];         // [i][fo]

  int t = threadIdx.x;
  int pg = t / TPG;
  int tg = t % TPG;
  int bg = tg / 32;          // 0..NBG-1
  int fg = tg % 32;          // fo4 index
  int g = blockIdx.x * PG + pg;
  if (g >= NPOOL) g = NPOOL - 1;   // tail blocks recompute last group (benign duplicate writes)

  float4 bias4 = *(const float4*)&bias[fg * 4];

  float pooled[BTILE][4];
  #pragma unroll
  for (int ii = 0; ii < BTILE; ++ii)
    #pragma unroll
    for (int jj = 0; jj < 4; ++jj) pooled[ii][jj] = 0.f;   // ReLU floor

  for (int nd = 0; nd < POOLSZ; ++nd) {
    int n = g * POOLSZ + nd;
    __syncthreads();   // As reuse from previous node
    // stage As[pg][(f*5+k)*BB + b] from the 5 term slices
    #pragma unroll
    for (int k = 0; k < POLY_K; ++k) {
      const float* src = slices + (size_t)k * SLICE + (size_t)n * CB;
      for (int i = tg * 4; i < CB; i += TPG * 4) {
        int b = i >> 6;
        int f = i & 63;
        float4 v = *(const float4*)(src + i);
        As[pg][((f + 0) * POLY_K + k) * BB + b] = v.x;
        As[pg][((f + 1) * POLY_K + k) * BB + b] = v.y;
        As[pg][((f + 2) * POLY_K + k) * BB + b] = v.z;
        As[pg][((f + 3) * POLY_K + k) * BB + b] = v.w;
      }
    }

    float acc[BTILE][4];
    #pragma unroll
    for (int ii = 0; ii < BTILE; ++ii)
      #pragma unroll
      for (int jj = 0; jj < 4; ++jj) acc[ii][jj] = 0.f;

    for (int kc = 0; kc < KTOT; kc += KC) {
      __syncthreads();   // Ws reuse / As visibility on first chunk
      for (int p = t * 4; p < KC * OUT_FEAT; p += 1024)
        *(float4*)&Ws[p] = *(const float4*)&weight[kc * OUT_FEAT + p];
      __syncthreads();
      #pragma unroll 8
      for (int i = 0; i < KC; ++i) {
        int kk = kc + i;
        float a_s[BTILE];
        #pragma unroll
        for (int bb = 0; bb < BTILE; ++bb)
          a_s[bb] = As[pg][kk * BB + bg * BTILE + bb];
        float4 w4 = *(const float4*)&Ws[i * OUT_FEAT + fg * 4];
        #pragma unroll
        for (int bb = 0; bb < BTILE; ++bb) {
          acc[bb][0] += a_s[bb] * w4.x;
          acc[bb][1] += a_s[bb] * w4.y;
          acc[bb][2] += a_s[bb] * w4.z;
          acc[bb][3] += a_s[bb] * w4.w;
        }
      }
    }

    #pragma unroll
    for (int ii = 0; ii < BTILE; ++ii) {
      pooled[ii][0] = fmaxf(pooled[ii][0], acc[ii][0] + bias4.x);
      pooled[ii][1] = fmaxf(pooled[ii][1], acc[ii][1] + bias4.y);
      pooled[ii][2] = fmaxf(pooled[ii][2], acc[ii][2] + bias4.z);
      pooled[ii][3] = fmaxf(pooled[ii][3], acc[ii][3] + bias4.w);
    }
  }

  #pragma unroll
  for (int ii = 0; ii < BTILE; ++ii) {
    int b = b0 + bg * BTILE + ii;
    float4 o;
    o.x = pooled[ii][0]; o.y = pooled[ii][1]; o.z = pooled[ii][2]; o.w = pooled[ii][3];
    *(float4*)&out[((size_t)b * NPOOL + g) * OUT_FEAT + fg * 4] = o;
  }
}

// ---------------- pipeline ----------------

template <int BB>
static void run_pipeline(const float* x, const float* weight, const float* bias,
                         const int* row_start, const int* csr_cols, const float* csr_vals,
                         float* slices, float* out, hipStream_t stream) {
  constexpr int CB = 64 * BB;
  constexpr size_t SLICE = (size_t)N_NODES * CB;
  constexpr int PG = 256 / ((BB >= 4 ? BB / 4 : 1) * 32);
  for (int b0 = 0; b0 < BATCH; b0 += BB) {
    transpose_kernel<BB><<<N_NODES, 256, 0, stream>>>(x, slices, b0);
    for (int k = 1; k < POLY_K; ++k) {
      const float* xin  = slices + (size_t)(k - 1) * SLICE;
      const float* prev = (k >= 2) ? slices + (size_t)(k - 2) * SLICE : slices;
      float* xout = slices + (size_t)k * SLICE;
      float alpha = (k == 1) ? 1.0f : 2.0f;
      spmm_kernel<BB><<<N_NODES, 64, 0, stream>>>(xin, prev, xout, row_start,
                                                  csr_cols, csr_vals, alpha, (k >= 2) ? 1 : 0);
    }
    gemm_kernel<BB><<<(NPOOL + PG - 1) / PG, 256, 0, stream>>>(slices, weight, bias, out, b0);
  }
}

static size_t needed_bytes(int BB) {
  return (size_t)(10016 * 3 + N_EDGES * 2 + 5 * N_NODES * 64 * BB) * 4;
}

extern "C" void kernel_launch(void* const* d_in, const int* in_sizes, int n_in,
                              void* d_out, int out_size, void* d_ws, size_t ws_size,
                              hipStream_t stream) {
  const float* x        = (const float*)d_in[0];
  const int*   lap_rows = (const int*)d_in[1];
  const int*   lap_cols = (const int*)d_in[2];
  const float* lap_vals = (const float*)d_in[3];
  const float* weight   = (const float*)d_in[4];
  const float* bias     = (const float*)d_in[5];
  float* out = (float*)d_out;

  int* deg       = (int*)d_ws;
  int* cursor    = deg + 10016;
  int* row_start = cursor + 10016;
  int* csr_cols  = row_start + 10016;
  float* csr_vals = (float*)(csr_cols + N_EDGES);
  float* slices   = csr_vals + N_EDGES;

  int BB = 0;
  if      (ws_size >= needed_bytes(8)) BB = 8;
  else if (ws_size >= needed_bytes(4)) BB = 4;
  else if (ws_size >= needed_bytes(2)) BB = 2;
  else if (ws_size >= needed_bytes(1)) BB = 1;
  if (BB == 0) return;   // < 14.3 MB workspace: cannot run

  zero_int_kernel<<<(N_NODES + 255) / 256, 256, 0, stream>>>(deg, N_NODES);
  hist_kernel<<<(N_EDGES + 255) / 256, 256, 0, stream>>>(lap_rows, deg);
  scan_kernel<<<1, 1024, 0, stream>>>(deg, row_start, cursor);
  scatter_kernel<<<(N_EDGES + 255) / 256, 256, 0, stream>>>(lap_rows, lap_cols, lap_vals,
                                                            cursor, csr_cols, csr_vals);

  switch (BB) {
    case 8: run_pipeline<8>(x, weight, bias, row_start, csr_cols, csr_vals, slices, out, stream); break;
    case 4: run_pipeline<4>(x, weight, bias, row_start, csr_cols, csr_vals, slices, out, stream); break;
    case 2: run_pipeline<2>(x, weight, bias, row_start, csr_cols, csr_vals, slices, out, stream); break;
    case 1: run_pipeline<1>(x, weight, bias, row_start, csr_cols, csr_vals, slices, out, stream); break;
  }
}

// Round 4
// 1138.357 us; speedup vs baseline: 1.5037x; 1.5037x over previous
//
#include <hip/hip_runtime.h>
#include <hip/hip_bf16.h>
#include <cstddef>
#include <cstdint>

#define N_NODES 10000
#define N_EDGES 160000
#define BATCH 32
#define IN_FEAT 64
#define POLY_K 5
#define OUT_FEAT 128
#define KTOT 320               // IN_FEAT * POLY_K
#define POOLSZ 4
#define NPOOL 2500
#define KPAD 328               // bf16 LDS row stride: 656 B = 164 words; 164%32=4 -> 2-way (free)

typedef short bf16x8 __attribute__((ext_vector_type(8)));
typedef float f32x4 __attribute__((ext_vector_type(4)));

__device__ __forceinline__ unsigned short f2bf(float f) {
  unsigned int u = __float_as_uint(f);
  unsigned int r = u + 0x7FFFu + ((u >> 16) & 1u);   // RNE
  return (unsigned short)(r >> 16);
}

// ---------------- CSR build ----------------

__global__ void zero_int_kernel(int* __restrict__ p, int n) {
  int i = blockIdx.x * 256 + threadIdx.x;
  if (i < n) p[i] = 0;
}

__global__ void hist_kernel(const int* __restrict__ rows, int* __restrict__ deg) {
  int e = blockIdx.x * 256 + threadIdx.x;
  if (e < N_EDGES) atomicAdd(&deg[rows[e]], 1);
}

__global__ void scan_kernel(const int* __restrict__ deg, int* __restrict__ row_start,
                            int* __restrict__ cursor) {
  __shared__ int sm[1024];
  __shared__ int carry;
  int t = threadIdx.x;
  if (t == 0) { carry = 0; row_start[0] = 0; }
  __syncthreads();
  for (int base = 0; base < N_NODES; base += 1024) {
    int idx = base + t;
    int v = (idx < N_NODES) ? deg[idx] : 0;
    sm[t] = v;
    __syncthreads();
    for (int off = 1; off < 1024; off <<= 1) {
      int xv = 0;
      if (t >= off) xv = sm[t - off];
      __syncthreads();
      sm[t] += xv;
      __syncthreads();
    }
    if (idx < N_NODES) {
      int incl = sm[t];
      row_start[idx + 1] = carry + incl;
      cursor[idx] = carry + incl - v;
    }
    __syncthreads();
    if (t == 1023) carry += sm[1023];
    __syncthreads();
  }
}

__global__ void scatter_kernel(const int* __restrict__ rows, const int* __restrict__ cols,
                               const float* __restrict__ vals, int* __restrict__ cursor,
                               int* __restrict__ csr_cols, float* __restrict__ csr_vals) {
  int e = blockIdx.x * 256 + threadIdx.x;
  if (e < N_EDGES) {
    int r = rows[e];
    int p = atomicAdd(&cursor[r], 1);
    csr_cols[p] = cols[e];
    csr_vals[p] = vals[e];
  }
}

// ---------------- weight prepack: B-fragment lane order, k' = kpoly*64+f ----------------
// wpack[((ft*10 + c)*64 + l)*8 + j] = bf16( W[(k&63)*5 + (k>>6)][ft*16 + (l&15)] ),
//   k = c*32 + (l>>4)*8 + j

__global__ void wpack_kernel(const float* __restrict__ weight, unsigned short* __restrict__ wpack) {
  int id = blockIdx.x * 256 + threadIdx.x;      // 8*10*64 = 5120 lane-slots
  if (id >= 5120) return;
  int ft = id / 640;
  int c = (id / 64) % 10;
  int l = id % 64;
  int fo = ft * 16 + (l & 15);
  unsigned short v[8];
  #pragma unroll
  for (int j = 0; j < 8; ++j) {
    int k = c * 32 + ((l >> 4)) * 8 + j;
    int row = (k & 63) * POLY_K + (k >> 6);
    v[j] = f2bf(weight[row * OUT_FEAT + fo]);
  }
  ushort4* dst = (ushort4*)&wpack[(size_t)id * 8];
  dst[0] = make_ushort4(v[0], v[1], v[2], v[3]);
  dst[1] = make_ushort4(v[4], v[5], v[6], v[7]);
}

// ---------------- transpose: slice0[n][b*64+f] = x[b0+b][n][f] ----------------

template <int BB>
__global__ void transpose_kernel(const float* __restrict__ x, float* __restrict__ t0, int b0) {
  constexpr int CB = 64 * BB;
  int n = blockIdx.x;
  int t = threadIdx.x;
  #pragma unroll
  for (int i = t * 4; i < CB; i += 1024) {
    int b = i >> 6;
    float4 v = *(const float4*)&x[((size_t)(b0 + b) * N_NODES + n) * IN_FEAT + (i & 63)];
    *(float4*)&t0[(size_t)n * CB + i] = v;
  }
}

// ---------------- SpMM: xout[n,:] = alpha * sum val*xin[col,:] (- prev[n,:]) ----------------

template <int BB>
__global__ void spmm_kernel(const float* __restrict__ xin, const float* __restrict__ prev,
                            float* __restrict__ xout,
                            const int* __restrict__ row_start,
                            const int* __restrict__ csr_cols, const float* __restrict__ csr_vals,
                            float alpha, int use_prev) {
  constexpr int CB = 64 * BB;
  constexpr int NV = (CB + 255) / 256;
  int n = blockIdx.x;
  int t = threadIdx.x;
  int s = row_start[n];
  int e = row_start[n + 1];
  float4 acc[NV];
  #pragma unroll
  for (int j = 0; j < NV; ++j) acc[j] = make_float4(0.f, 0.f, 0.f, 0.f);
  for (int i = s; i < e; ++i) {
    int col = csr_cols[i];
    float v = csr_vals[i];
    const float* src = xin + (size_t)col * CB;
    #pragma unroll
    for (int j = 0; j < NV; ++j) {
      int c = t * 4 + j * 256;
      if (c < CB) {
        float4 p = *(const float4*)(src + c);
        acc[j].x += v * p.x; acc[j].y += v * p.y;
        acc[j].z += v * p.z; acc[j].w += v * p.w;
      }
    }
  }
  #pragma unroll
  for (int j = 0; j < NV; ++j) {
    int c = t * 4 + j * 256;
    if (c < CB) {
      float4 r;
      r.x = alpha * acc[j].x; r.y = alpha * acc[j].y;
      r.z = alpha * acc[j].z; r.w = alpha * acc[j].w;
      if (use_prev) {
        float4 q = *(const float4*)(prev + (size_t)n * CB + c);
        r.x -= q.x; r.y -= q.y; r.z -= q.z; r.w -= q.w;
      }
      *(float4*)(xout + (size_t)n * CB + c) = r;
    }
  }
}

// ---------------- MFMA GEMM + bias + ReLU + maxpool(4), one pooled group per block ------------
// m = b*4 + nd  =>  C/D's 4 regs per lane are the 4 pool elements of one b (in-lane maxpool).

template <int BB>
__global__ __launch_bounds__(256) void gemm_mfma_kernel(const float* __restrict__ slices,
                                                        const unsigned short* __restrict__ wpack,
                                                        const float* __restrict__ bias,
                                                        float* __restrict__ out, int b0) {
  constexpr int CB = 64 * BB;
  constexpr int MT = (BB >= 4) ? BB / 4 : 1;       // number of 16-row M-tiles
  constexpr size_t SLICE = (size_t)N_NODES * CB;
  __shared__ unsigned short A[4 * BB * KPAD];      // [m][k'] bf16, padded rows

  int g = blockIdx.x;
  int t = threadIdx.x;

  // stage A: A[m = b*4+nd][k' = kpoly*64+f] = bf16(T_kpoly[g*4+nd][b*64+f])
  constexpr int SLOTS = 320 * BB;                  // float4 slots
  #pragma unroll
  for (int s = 0; s < SLOTS / 256; ++s) {
    int idx = s * 256 + t;
    int kpoly = idx / CB;
    int r = idx % CB;
    int nd = r / (16 * BB);
    int r2 = r % (16 * BB);
    int b = r2 / 16;
    int f4 = r2 % 16;
    float4 v = *(const float4*)&slices[(size_t)kpoly * SLICE +
                                       (size_t)(g * POOLSZ + nd) * CB + b * 64 + f4 * 4];
    int m = b * 4 + nd;
    ushort4 pk = make_ushort4(f2bf(v.x), f2bf(v.y), f2bf(v.z), f2bf(v.w));
    *(ushort4*)&A[m * KPAD + kpoly * 64 + f4 * 4] = pk;
  }
  __syncthreads();

  int w = t >> 6;          // wave 0..3: fo-tiles {2w, 2w+1}
  int l = t & 63;
  int lm = l & 15;
  int q = l >> 4;

  f32x4 acc[MT][2];
  #pragma unroll
  for (int mt = 0; mt < MT; ++mt)
    #pragma unroll
    for (int fj = 0; fj < 2; ++fj) {
      acc[mt][fj][0] = 0.f; acc[mt][fj][1] = 0.f;
      acc[mt][fj][2] = 0.f; acc[mt][fj][3] = 0.f;
    }

  #pragma unroll
  for (int c = 0; c < 10; ++c) {
    bf16x8 bfrag[2];
    #pragma unroll
    for (int fj = 0; fj < 2; ++fj) {
      int fi = w * 2 + fj;
      bfrag[fj] = *(const bf16x8*)&wpack[(size_t)(((fi * 10) + c) * 64 + l) * 8];
    }
    #pragma unroll
    for (int mt = 0; mt < MT; ++mt) {
      bf16x8 afrag = *(const bf16x8*)&A[(mt * 16 + lm) * KPAD + c * 32 + q * 8];
      acc[mt][0] = __builtin_amdgcn_mfma_f32_16x16x32_bf16(afrag, bfrag[0], acc[mt][0], 0, 0, 0);
      acc[mt][1] = __builtin_amdgcn_mfma_f32_16x16x32_bf16(afrag, bfrag[1], acc[mt][1], 0, 0, 0);
    }
  }

  // epilogue: in-lane maxpool over the 4 regs (nd), +bias, ReLU
  #pragma unroll
  for (int fj = 0; fj < 2; ++fj) {
    int fo = (w * 2 + fj) * 16 + lm;
    float bv = bias[fo];
    #pragma unroll
    for (int mt = 0; mt < MT; ++mt) {
      float mx = fmaxf(fmaxf(acc[mt][fj][0], acc[mt][fj][1]),
                       fmaxf(acc[mt][fj][2], acc[mt][fj][3]));
      float val = fmaxf(mx + bv, 0.f);
      int b = b0 + mt * 4 + q;
      out[((size_t)b * NPOOL + g) * OUT_FEAT + fo] = val;
    }
  }
}

// ---------------- fallback VALU GEMM for BB<4 ----------------

#define KC 40

template <int BB>
__global__ __launch_bounds__(256) void gemm_kernel(const float* __restrict__ slices,
                                                   const float* __restrict__ weight,
                                                   const float* __restrict__ bias,
                                                   float* __restrict__ out, int b0) {
  constexpr int CB = 64 * BB;
  constexpr int BTILE = (BB >= 4) ? 4 : BB;
  constexpr int NBG = BB / BTILE;
  constexpr int TPG = NBG * 32;
  constexpr int PG = 256 / TPG;
  constexpr size_t SLICE = (size_t)N_NODES * CB;

  __shared__ float As[PG][KTOT * BB];
  __shared__ float Ws[KC * OUT_FEAT];

  int t = threadIdx.x;
  int pg = t / TPG;
  int tg = t % TPG;
  int bg = tg / 32;
  int fg = tg % 32;
  int g = blockIdx.x * PG + pg;
  if (g >= NPOOL) g = NPOOL - 1;

  float4 bias4 = *(const float4*)&bias[fg * 4];

  float pooled[BTILE][4];
  #pragma unroll
  for (int ii = 0; ii < BTILE; ++ii)
    #pragma unroll
    for (int jj = 0; jj < 4; ++jj) pooled[ii][jj] = 0.f;

  for (int nd = 0; nd < POOLSZ; ++nd) {
    int n = g * POOLSZ + nd;
    __syncthreads();
    #pragma unroll
    for (int k = 0; k < POLY_K; ++k) {
      const float* src = slices + (size_t)k * SLICE + (size_t)n * CB;
      for (int i = tg * 4; i < CB; i += TPG * 4) {
        int b = i >> 6;
        int f = i & 63;
        float4 v = *(const float4*)(src + i);
        As[pg][((f + 0) * POLY_K + k) * BB + b] = v.x;
        As[pg][((f + 1) * POLY_K + k) * BB + b] = v.y;
        As[pg][((f + 2) * POLY_K + k) * BB + b] = v.z;
        As[pg][((f + 3) * POLY_K + k) * BB + b] = v.w;
      }
    }

    float acc[BTILE][4];
    #pragma unroll
    for (int ii = 0; ii < BTILE; ++ii)
      #pragma unroll
      for (int jj = 0; jj < 4; ++jj) acc[ii][jj] = 0.f;

    for (int kc = 0; kc < KTOT; kc += KC) {
      __syncthreads();
      for (int p = t * 4; p < KC * OUT_FEAT; p += 1024)
        *(float4*)&Ws[p] = *(const float4*)&weight[kc * OUT_FEAT + p];
      __syncthreads();
      #pragma unroll 8
      for (int i = 0; i < KC; ++i) {
        int kk = kc + i;
        float a_s[BTILE];
        #pragma unroll
        for (int bb = 0; bb < BTILE; ++bb)
          a_s[bb] = As[pg][kk * BB + bg * BTILE + bb];
        float4 w4 = *(const float4*)&Ws[i * OUT_FEAT + fg * 4];
        #pragma unroll
        for (int bb = 0; bb < BTILE; ++bb) {
          acc[bb][0] += a_s[bb] * w4.x;
          acc[bb][1] += a_s[bb] * w4.y;
          acc[bb][2] += a_s[bb] * w4.z;
          acc[bb][3] += a_s[bb] * w4.w;
        }
      }
    }

    #pragma unroll
    for (int ii = 0; ii < BTILE; ++ii) {
      pooled[ii][0] = fmaxf(pooled[ii][0], acc[ii][0] + bias4.x);
      pooled[ii][1] = fmaxf(pooled[ii][1], acc[ii][1] + bias4.y);
      pooled[ii][2] = fmaxf(pooled[ii][2], acc[ii][2] + bias4.z);
      pooled[ii][3] = fmaxf(pooled[ii][3], acc[ii][3] + bias4.w);
    }
  }

  #pragma unroll
  for (int ii = 0; ii < BTILE; ++ii) {
    int b = b0 + bg * BTILE + ii;
    float4 o;
    o.x = pooled[ii][0]; o.y = pooled[ii][1]; o.z = pooled[ii][2]; o.w = pooled[ii][3];
    *(float4*)&out[((size_t)b * NPOOL + g) * OUT_FEAT + fg * 4] = o;
  }
}

// ---------------- pipeline ----------------

template <int BB>
static void run_pipeline(const float* x, const float* weight, const float* bias,
                         const int* row_start, const int* csr_cols, const float* csr_vals,
                         const unsigned short* wpack,
                         float* slices, float* out, hipStream_t stream) {
  constexpr int CB = 64 * BB;
  constexpr size_t SLICE = (size_t)N_NODES * CB;
  for (int b0 = 0; b0 < BATCH; b0 += BB) {
    transpose_kernel<BB><<<N_NODES, 256, 0, stream>>>(x, slices, b0);
    for (int k = 1; k < POLY_K; ++k) {
      const float* xin  = slices + (size_t)(k - 1) * SLICE;
      const float* prev = (k >= 2) ? slices + (size_t)(k - 2) * SLICE : slices;
      float* xout = slices + (size_t)k * SLICE;
      float alpha = (k == 1) ? 1.0f : 2.0f;
      spmm_kernel<BB><<<N_NODES, 64, 0, stream>>>(xin, prev, xout, row_start,
                                                  csr_cols, csr_vals, alpha, (k >= 2) ? 1 : 0);
    }
    if constexpr (BB >= 4) {
      gemm_mfma_kernel<BB><<<NPOOL, 256, 0, stream>>>(slices, wpack, bias, out, b0);
    } else {
      constexpr int PG = 256 / ((BB >= 4 ? BB / 4 : 1) * 32);
      gemm_kernel<BB><<<(NPOOL + PG - 1) / PG, 256, 0, stream>>>(slices, weight, bias, out, b0);
    }
  }
}

static size_t needed_bytes(int BB) {
  return (size_t)(10016 * 3 + N_EDGES * 2 + 20480 + 5 * N_NODES * 64 * BB) * 4;
}

extern "C" void kernel_launch(void* const* d_in, const int* in_sizes, int n_in,
                              void* d_out, int out_size, void* d_ws, size_t ws_size,
                              hipStream_t stream) {
  const float* x        = (const float*)d_in[0];
  const int*   lap_rows = (const int*)d_in[1];
  const int*   lap_cols = (const int*)d_in[2];
  const float* lap_vals = (const float*)d_in[3];
  const float* weight   = (const float*)d_in[4];
  const float* bias     = (const float*)d_in[5];
  float* out = (float*)d_out;

  int* deg       = (int*)d_ws;
  int* cursor    = deg + 10016;
  int* row_start = cursor + 10016;
  int* csr_cols  = row_start + 10016;
  float* csr_vals = (float*)(csr_cols + N_EDGES);
  unsigned short* wpack = (unsigned short*)(csr_vals + N_EDGES);   // 40960 ushort = 81920 B
  float* slices   = (float*)(wpack + 40960);

  int BB = 0;
  if      (ws_size >= needed_bytes(16)) BB = 16;
  else if (ws_size >= needed_bytes(8))  BB = 8;
  else if (ws_size >= needed_bytes(4))  BB = 4;
  else if (ws_size >= needed_bytes(2))  BB = 2;
  else if (ws_size >= needed_bytes(1))  BB = 1;
  if (BB == 0) return;

  zero_int_kernel<<<(N_NODES + 255) / 256, 256, 0, stream>>>(deg, N_NODES);
  hist_kernel<<<(N_EDGES + 255) / 256, 256, 0, stream>>>(lap_rows, deg);
  scan_kernel<<<1, 1024, 0, stream>>>(deg, row_start, cursor);
  scatter_kernel<<<(N_EDGES + 255) / 256, 256, 0, stream>>>(lap_rows, lap_cols, lap_vals,
                                                            cursor, csr_cols, csr_vals);
  wpack_kernel<<<20, 256, 0, stream>>>(weight, wpack);

  switch (BB) {
    case 16: run_pipeline<16>(x, weight, bias, row_start, csr_cols, csr_vals, wpack, slices, out, stream); break;
    case 8:  run_pipeline<8>(x, weight, bias, row_start, csr_cols, csr_vals, wpack, slices, out, stream); break;
    case 4:  run_pipeline<4>(x, weight, bias, row_start, csr_cols, csr_vals, wpack, slices, out, stream); break;
    case 2:  run_pipeline<2>(x, weight, bias, row_start, csr_cols, csr_vals, wpack, slices, out, stream); break;
    case 1:  run_pipeline<1>(x, weight, bias, row_start, csr_cols, csr_vals, wpack, slices, out, stream); break;
  }
}

// Round 5
// 627.469 us; speedup vs baseline: 2.7280x; 1.8142x over previous
//
#include <hip/hip_runtime.h>
#include <hip/hip_bf16.h>
#include <cstddef>
#include <cstdint>

#define N_NODES 10000
#define N_EDGES 160000
#define BATCH 32
#define IN_FEAT 64
#define POLY_K 5
#define OUT_FEAT 128
#define KTOT 320               // IN_FEAT * POLY_K
#define POOLSZ 4
#define NPOOL 2500
#define KPAD 328               // bf16 LDS row stride (ushorts); 328*2/4=164 words, 164%32=4

typedef short bf16x8 __attribute__((ext_vector_type(8)));
typedef unsigned short u16x8 __attribute__((ext_vector_type(8)));
typedef float f32x4 __attribute__((ext_vector_type(4)));

__device__ __forceinline__ unsigned short f2bf(float f) {
  unsigned int u = __float_as_uint(f);
  unsigned int r = u + 0x7FFFu + ((u >> 16) & 1u);   // RNE
  return (unsigned short)(r >> 16);
}
__device__ __forceinline__ float bf2f(unsigned short u) {
  return __uint_as_float(((unsigned int)u) << 16);
}

// ---------------- CSR build ----------------

__global__ void zero_int_kernel(int* __restrict__ p, int n) {
  int i = blockIdx.x * 256 + threadIdx.x;
  if (i < n) p[i] = 0;
}

__global__ void hist_kernel(const int* __restrict__ rows, int* __restrict__ deg) {
  int e = blockIdx.x * 256 + threadIdx.x;
  if (e < N_EDGES) atomicAdd(&deg[rows[e]], 1);
}

__global__ void scan_kernel(const int* __restrict__ deg, int* __restrict__ row_start,
                            int* __restrict__ cursor) {
  __shared__ int sm[1024];
  __shared__ int carry;
  int t = threadIdx.x;
  if (t == 0) { carry = 0; row_start[0] = 0; }
  __syncthreads();
  for (int base = 0; base < N_NODES; base += 1024) {
    int idx = base + t;
    int v = (idx < N_NODES) ? deg[idx] : 0;
    sm[t] = v;
    __syncthreads();
    for (int off = 1; off < 1024; off <<= 1) {
      int xv = 0;
      if (t >= off) xv = sm[t - off];
      __syncthreads();
      sm[t] += xv;
      __syncthreads();
    }
    if (idx < N_NODES) {
      int incl = sm[t];
      row_start[idx + 1] = carry + incl;
      cursor[idx] = carry + incl - v;
    }
    __syncthreads();
    if (t == 1023) carry += sm[1023];
    __syncthreads();
  }
}

__global__ void scatter_kernel(const int* __restrict__ rows, const int* __restrict__ cols,
                               const float* __restrict__ vals, int* __restrict__ cursor,
                               int* __restrict__ csr_cols, float* __restrict__ csr_vals) {
  int e = blockIdx.x * 256 + threadIdx.x;
  if (e < N_EDGES) {
    int r = rows[e];
    int p = atomicAdd(&cursor[r], 1);
    csr_cols[p] = cols[e];
    csr_vals[p] = vals[e];
  }
}

// ---------------- weight prepack: B-fragment lane order, k' = kpoly*64+f ----------------

__global__ void wpack_kernel(const float* __restrict__ weight, unsigned short* __restrict__ wpack) {
  int id = blockIdx.x * 256 + threadIdx.x;      // 8*10*64 = 5120 lane-slots
  if (id >= 5120) return;
  int ft = id / 640;
  int c = (id / 64) % 10;
  int l = id % 64;
  int fo = ft * 16 + (l & 15);
  unsigned short v[8];
  #pragma unroll
  for (int j = 0; j < 8; ++j) {
    int k = c * 32 + ((l >> 4)) * 8 + j;
    int row = (k & 63) * POLY_K + (k >> 6);
    v[j] = f2bf(weight[row * OUT_FEAT + fo]);
  }
  ushort4* dst = (ushort4*)&wpack[(size_t)id * 8];
  dst[0] = make_ushort4(v[0], v[1], v[2], v[3]);
  dst[1] = make_ushort4(v[4], v[5], v[6], v[7]);
}

// ---------------- transpose: slice0[n][b*64+f] = bf16(x[b0+b][n][f]) ----------------

template <int BB>
__global__ __launch_bounds__(256) void transpose_kernel(const float* __restrict__ x,
                                                        unsigned short* __restrict__ t0, int b0) {
  constexpr int CB = 64 * BB;
  int n = blockIdx.x;
  int t = threadIdx.x;
  for (int i = t * 8; i < CB; i += 2048) {
    int b = i >> 6;
    int f = i & 63;
    const float* xp = &x[((size_t)(b0 + b) * N_NODES + n) * IN_FEAT + f];
    float4 v0 = *(const float4*)xp;
    float4 v1 = *(const float4*)(xp + 4);
    u16x8 o;
    o[0] = f2bf(v0.x); o[1] = f2bf(v0.y); o[2] = f2bf(v0.z); o[3] = f2bf(v0.w);
    o[4] = f2bf(v1.x); o[5] = f2bf(v1.y); o[6] = f2bf(v1.z); o[7] = f2bf(v1.w);
    *(u16x8*)&t0[(size_t)n * CB + i] = o;
  }
}

// ---------------- SpMM (bf16): xout[n,:] = bf16(alpha * sum val*xin[col,:] - prev[n,:]) --------

template <int BB>
__global__ __launch_bounds__(256) void spmm_kernel(const unsigned short* __restrict__ xin,
                                                   const unsigned short* __restrict__ prev,
                                                   unsigned short* __restrict__ xout,
                                                   const int* __restrict__ row_start,
                                                   const int* __restrict__ csr_cols,
                                                   const float* __restrict__ csr_vals,
                                                   float alpha, int use_prev) {
  constexpr int CB = 64 * BB;
  constexpr int LPR = CB / 8;          // lanes per row (8 bf16 cols each)
  constexpr int RPB = 256 / LPR;       // rows per block (>=1 for BB<=32)
  int t = threadIdx.x;
  int rl = (RPB > 1) ? (t / LPR) : 0;
  int cl = (RPB > 1) ? (t % LPR) : t;
  int n = blockIdx.x * RPB + rl;
  int off = cl * 8;

  int s = row_start[n];
  int e = row_start[n + 1];
  float acc[8];
  #pragma unroll
  for (int j = 0; j < 8; ++j) acc[j] = 0.f;

  int i = s;
  for (; i + 3 < e; i += 4) {
    int c0 = csr_cols[i + 0], c1 = csr_cols[i + 1];
    int c2 = csr_cols[i + 2], c3 = csr_cols[i + 3];
    float v0 = csr_vals[i + 0], v1 = csr_vals[i + 1];
    float v2 = csr_vals[i + 2], v3 = csr_vals[i + 3];
    u16x8 p0 = *(const u16x8*)&xin[(size_t)c0 * CB + off];
    u16x8 p1 = *(const u16x8*)&xin[(size_t)c1 * CB + off];
    u16x8 p2 = *(const u16x8*)&xin[(size_t)c2 * CB + off];
    u16x8 p3 = *(const u16x8*)&xin[(size_t)c3 * CB + off];
    #pragma unroll
    for (int j = 0; j < 8; ++j) {
      acc[j] = fmaf(v0, bf2f(p0[j]), acc[j]);
      acc[j] = fmaf(v1, bf2f(p1[j]), acc[j]);
      acc[j] = fmaf(v2, bf2f(p2[j]), acc[j]);
      acc[j] = fmaf(v3, bf2f(p3[j]), acc[j]);
    }
  }
  for (; i < e; ++i) {
    int c0 = csr_cols[i];
    float v0 = csr_vals[i];
    u16x8 p0 = *(const u16x8*)&xin[(size_t)c0 * CB + off];
    #pragma unroll
    for (int j = 0; j < 8; ++j) acc[j] = fmaf(v0, bf2f(p0[j]), acc[j]);
  }

  u16x8 o;
  if (use_prev) {
    u16x8 q = *(const u16x8*)&prev[(size_t)n * CB + off];
    #pragma unroll
    for (int j = 0; j < 8; ++j) o[j] = f2bf(alpha * acc[j] - bf2f(q[j]));
  } else {
    #pragma unroll
    for (int j = 0; j < 8; ++j) o[j] = f2bf(alpha * acc[j]);
  }
  *(u16x8*)&xout[(size_t)n * CB + off] = o;
}

// ---------------- MFMA GEMM + bias + ReLU + maxpool(4) ----------------
// grid = (NPOOL, BB/MB). Block handles pooled group g, batch half bh (MB b's).
// m = bloc*4 + nd  =>  C/D's 4 regs per lane = 4 pool elements of one b (in-lane maxpool).

template <int BB>
__global__ __launch_bounds__(256) void gemm_mfma_kernel(const unsigned short* __restrict__ slices,
                                                        const unsigned short* __restrict__ wpack,
                                                        const float* __restrict__ bias,
                                                        float* __restrict__ out, int b0) {
  constexpr int CB = 64 * BB;
  constexpr int MB = (BB >= 16) ? 16 : BB;        // b's per block
  constexpr int MT = MB / 4;                      // 16-row M-tiles
  constexpr int SPAN = MB * 64;                   // cols per block
  constexpr size_t SLICE = (size_t)N_NODES * CB;
  __shared__ unsigned short A[4 * MB * KPAD];

  int g = blockIdx.x;
  int bh = blockIdx.y;
  int t = threadIdx.x;

  // stage A[m = bloc*4+nd][k' = kpoly*64+f] = T_kpoly[g*4+nd][(bh*MB+bloc)*64+f]
  constexpr int SLOTS = POLY_K * 4 * (SPAN / 8);  // ushort8 slots
  for (int idx = t; idx < SLOTS; idx += 256) {
    int kpoly = idx / (4 * (SPAN / 8));
    int r = idx % (4 * (SPAN / 8));
    int nd = r / (SPAN / 8);
    int colloc = (r % (SPAN / 8)) * 8;
    int bloc = colloc >> 6;
    int f = colloc & 63;
    u16x8 v = *(const u16x8*)&slices[(size_t)kpoly * SLICE +
                                     (size_t)(g * POOLSZ + nd) * CB + bh * SPAN + colloc];
    *(u16x8*)&A[(bloc * 4 + nd) * KPAD + kpoly * 64 + f] = v;
  }
  __syncthreads();

  int w = t >> 6;          // wave 0..3: fo-tiles {2w, 2w+1}
  int l = t & 63;
  int lm = l & 15;
  int q = l >> 4;

  f32x4 acc[MT][2];
  #pragma unroll
  for (int mt = 0; mt < MT; ++mt)
    #pragma unroll
    for (int fj = 0; fj < 2; ++fj) {
      acc[mt][fj][0] = 0.f; acc[mt][fj][1] = 0.f;
      acc[mt][fj][2] = 0.f; acc[mt][fj][3] = 0.f;
    }

  #pragma unroll
  for (int c = 0; c < 10; ++c) {
    bf16x8 bfrag[2];
    #pragma unroll
    for (int fj = 0; fj < 2; ++fj) {
      int fi = w * 2 + fj;
      bfrag[fj] = *(const bf16x8*)&wpack[(size_t)(((fi * 10) + c) * 64 + l) * 8];
    }
    #pragma unroll
    for (int mt = 0; mt < MT; ++mt) {
      bf16x8 afrag = *(const bf16x8*)&A[(mt * 16 + lm) * KPAD + c * 32 + q * 8];
      acc[mt][0] = __builtin_amdgcn_mfma_f32_16x16x32_bf16(afrag, bfrag[0], acc[mt][0], 0, 0, 0);
      acc[mt][1] = __builtin_amdgcn_mfma_f32_16x16x32_bf16(afrag, bfrag[1], acc[mt][1], 0, 0, 0);
    }
  }

  // epilogue: in-lane maxpool over the 4 regs (nd), +bias, ReLU
  #pragma unroll
  for (int fj = 0; fj < 2; ++fj) {
    int fo = (w * 2 + fj) * 16 + lm;
    float bv = bias[fo];
    #pragma unroll
    for (int mt = 0; mt < MT; ++mt) {
      float mx = fmaxf(fmaxf(acc[mt][fj][0], acc[mt][fj][1]),
                       fmaxf(acc[mt][fj][2], acc[mt][fj][3]));
      float val = fmaxf(mx + bv, 0.f);
      int b = b0 + bh * MB + mt * 4 + q;
      out[((size_t)b * NPOOL + g) * OUT_FEAT + fo] = val;
    }
  }
}

// ---------------- pipeline ----------------

template <int BB>
static void run_pipeline(const float* x, const float* bias,
                         const int* row_start, const int* csr_cols, const float* csr_vals,
                         const unsigned short* wpack,
                         unsigned short* slices, float* out, hipStream_t stream) {
  constexpr int CB = 64 * BB;
  constexpr size_t SLICE = (size_t)N_NODES * CB;
  constexpr int RPB = 256 / (CB / 8) > 0 ? (256 / (CB / 8)) : 1;
  constexpr int MB = (BB >= 16) ? 16 : BB;
  for (int b0 = 0; b0 < BATCH; b0 += BB) {
    transpose_kernel<BB><<<N_NODES, 256, 0, stream>>>(x, slices, b0);
    for (int k = 1; k < POLY_K; ++k) {
      const unsigned short* xin  = slices + (size_t)(k - 1) * SLICE;
      const unsigned short* prev = (k >= 2) ? slices + (size_t)(k - 2) * SLICE : slices;
      unsigned short* xout = slices + (size_t)k * SLICE;
      float alpha = (k == 1) ? 1.0f : 2.0f;
      spmm_kernel<BB><<<N_NODES / RPB, 256, 0, stream>>>(xin, prev, xout, row_start,
                                                         csr_cols, csr_vals, alpha,
                                                         (k >= 2) ? 1 : 0);
    }
    gemm_mfma_kernel<BB><<<dim3(NPOOL, BB / MB), 256, 0, stream>>>(slices, wpack, bias, out, b0);
  }
}

static size_t needed_bytes(int BB) {
  return 1482112u + (size_t)6400000 * BB;   // CSR+wpack + 5*N*64*BB*2
}

extern "C" void kernel_launch(void* const* d_in, const int* in_sizes, int n_in,
                              void* d_out, int out_size, void* d_ws, size_t ws_size,
                              hipStream_t stream) {
  const float* x        = (const float*)d_in[0];
  const int*   lap_rows = (const int*)d_in[1];
  const int*   lap_cols = (const int*)d_in[2];
  const float* lap_vals = (const float*)d_in[3];
  const float* weight   = (const float*)d_in[4];
  const float* bias     = (const float*)d_in[5];
  float* out = (float*)d_out;

  int* deg       = (int*)d_ws;
  int* cursor    = deg + 10016;
  int* row_start = cursor + 10016;
  int* csr_cols  = row_start + 10016;
  float* csr_vals = (float*)(csr_cols + N_EDGES);
  unsigned short* wpack = (unsigned short*)(csr_vals + N_EDGES);   // 40960 ushorts
  unsigned short* slices = wpack + 40960;                          // bf16 terms

  int BB = 0;
  if      (ws_size >= needed_bytes(32)) BB = 32;   // 206.3 MB — proven to fit in R4
  else if (ws_size >= needed_bytes(16)) BB = 16;
  else if (ws_size >= needed_bytes(8))  BB = 8;
  else if (ws_size >= needed_bytes(4))  BB = 4;
  if (BB == 0) return;

  zero_int_kernel<<<(N_NODES + 255) / 256, 256, 0, stream>>>(deg, N_NODES);
  hist_kernel<<<(N_EDGES + 255) / 256, 256, 0, stream>>>(lap_rows, deg);
  scan_kernel<<<1, 1024, 0, stream>>>(deg, row_start, cursor);
  scatter_kernel<<<(N_EDGES + 255) / 256, 256, 0, stream>>>(lap_rows, lap_cols, lap_vals,
                                                            cursor, csr_cols, csr_vals);
  wpack_kernel<<<20, 256, 0, stream>>>(weight, wpack);

  switch (BB) {
    case 32: run_pipeline<32>(x, bias, row_start, csr_cols, csr_vals, wpack, slices, out, stream); break;
    case 16: run_pipeline<16>(x, bias, row_start, csr_cols, csr_vals, wpack, slices, out, stream); break;
    case 8:  run_pipeline<8>(x, bias, row_start, csr_cols, csr_vals, wpack, slices, out, stream); break;
    case 4:  run_pipeline<4>(x, bias, row_start, csr_cols, csr_vals, wpack, slices, out, stream); break;
  }
}

// Round 6
// 460.792 us; speedup vs baseline: 3.7147x; 1.3617x over previous
//
#include <hip/hip_runtime.h>
#include <hip/hip_bf16.h>
#include <cstddef>
#include <cstdint>

#define N_NODES 10000
#define N_EDGES 160000
#define BATCH 32
#define IN_FEAT 64
#define POLY_K 5
#define OUT_FEAT 128
#define KTOT 320               // IN_FEAT * POLY_K
#define POOLSZ 4
#define NPOOL 2500
#define KPAD 328               // bf16 LDS row stride (ushorts); 328*2/4=164 words, 164%32=4

typedef short bf16x8 __attribute__((ext_vector_type(8)));
typedef unsigned short u16x8 __attribute__((ext_vector_type(8)));
typedef float f32x4 __attribute__((ext_vector_type(4)));

__device__ __forceinline__ unsigned short f2bf(float f) {
  unsigned int u = __float_as_uint(f);
  unsigned int r = u + 0x7FFFu + ((u >> 16) & 1u);   // RNE
  return (unsigned short)(r >> 16);
}
__device__ __forceinline__ float bf2f(unsigned short u) {
  return __uint_as_float(((unsigned int)u) << 16);
}

// ---------------- CSR build ----------------

__global__ void zero_int_kernel(int* __restrict__ p, int n) {
  int i = blockIdx.x * 256 + threadIdx.x;
  if (i < n) p[i] = 0;
}

__global__ void hist_kernel(const int* __restrict__ rows, int* __restrict__ deg) {
  int e = blockIdx.x * 256 + threadIdx.x;
  if (e < N_EDGES) atomicAdd(&deg[rows[e]], 1);
}

__global__ void scan_kernel(const int* __restrict__ deg, int* __restrict__ row_start,
                            int* __restrict__ cursor) {
  __shared__ int sm[1024];
  __shared__ int carry;
  int t = threadIdx.x;
  if (t == 0) { carry = 0; row_start[0] = 0; }
  __syncthreads();
  for (int base = 0; base < N_NODES; base += 1024) {
    int idx = base + t;
    int v = (idx < N_NODES) ? deg[idx] : 0;
    sm[t] = v;
    __syncthreads();
    for (int off = 1; off < 1024; off <<= 1) {
      int xv = 0;
      if (t >= off) xv = sm[t - off];
      __syncthreads();
      sm[t] += xv;
      __syncthreads();
    }
    if (idx < N_NODES) {
      int incl = sm[t];
      row_start[idx + 1] = carry + incl;
      cursor[idx] = carry + incl - v;
    }
    __syncthreads();
    if (t == 1023) carry += sm[1023];
    __syncthreads();
  }
}

__global__ void scatter_kernel(const int* __restrict__ rows, const int* __restrict__ cols,
                               const float* __restrict__ vals, int* __restrict__ cursor,
                               int* __restrict__ csr_cols, float* __restrict__ csr_vals) {
  int e = blockIdx.x * 256 + threadIdx.x;
  if (e < N_EDGES) {
    int r = rows[e];
    int p = atomicAdd(&cursor[r], 1);
    csr_cols[p] = cols[e];
    csr_vals[p] = vals[e];
  }
}

// ---------------- weight prepack: B-fragment lane order, k' = kpoly*64+f ----------------

__global__ void wpack_kernel(const float* __restrict__ weight, unsigned short* __restrict__ wpack) {
  int id = blockIdx.x * 256 + threadIdx.x;      // 8*10*64 = 5120 lane-slots
  if (id >= 5120) return;
  int ft = id / 640;
  int c = (id / 64) % 10;
  int l = id % 64;
  int fo = ft * 16 + (l & 15);
  unsigned short v[8];
  #pragma unroll
  for (int j = 0; j < 8; ++j) {
    int k = c * 32 + ((l >> 4)) * 8 + j;
    int row = (k & 63) * POLY_K + (k >> 6);
    v[j] = f2bf(weight[row * OUT_FEAT + fo]);
  }
  ushort4* dst = (ushort4*)&wpack[(size_t)id * 8];
  dst[0] = make_ushort4(v[0], v[1], v[2], v[3]);
  dst[1] = make_ushort4(v[4], v[5], v[6], v[7]);
}

// ---------------- transpose: slice0[n][b*64+f] = bf16(x[b0+b][n][f]) ----------------

template <int BB>
__global__ __launch_bounds__(256) void transpose_kernel(const float* __restrict__ x,
                                                        unsigned short* __restrict__ t0, int b0) {
  constexpr int CB = 64 * BB;
  int n = blockIdx.x;
  int t = threadIdx.x;
  for (int i = t * 8; i < CB; i += 2048) {
    int b = i >> 6;
    int f = i & 63;
    const float* xp = &x[((size_t)(b0 + b) * N_NODES + n) * IN_FEAT + f];
    float4 v0 = *(const float4*)xp;
    float4 v1 = *(const float4*)(xp + 4);
    u16x8 o;
    o[0] = f2bf(v0.x); o[1] = f2bf(v0.y); o[2] = f2bf(v0.z); o[3] = f2bf(v0.w);
    o[4] = f2bf(v1.x); o[5] = f2bf(v1.y); o[6] = f2bf(v1.z); o[7] = f2bf(v1.w);
    *(u16x8*)&t0[(size_t)n * CB + i] = o;
  }
}

// ---------------- SpMM (bf16, XCD-sliced): 8 column slices pinned via blockIdx%8 ----------------
// xout[n, sl] = bf16(alpha * sum val*xin[col, sl] - prev[n, sl]); slice working set ~5 MB -> L2.

template <int BB>
__global__ __launch_bounds__(256) void spmm_kernel(const unsigned short* __restrict__ xin,
                                                   const unsigned short* __restrict__ prev,
                                                   unsigned short* __restrict__ xout,
                                                   const int* __restrict__ row_start,
                                                   const int* __restrict__ csr_cols,
                                                   const float* __restrict__ csr_vals,
                                                   float alpha, int use_prev) {
  constexpr int CB = 64 * BB;
  constexpr int SCOLS = CB / 8;         // cols per slice
  constexpr int LPR = SCOLS / 8;        // lanes per row-slice (8 bf16 each)
  constexpr int RPB = 256 / LPR;        // rows per block
  int bid = blockIdx.x;
  int slice = bid & 7;                  // XCD-pinning heuristic (round-robin dispatch)
  int rowblk = bid >> 3;
  int t = threadIdx.x;
  int rl = t / LPR;
  int cl = t % LPR;
  int n = rowblk * RPB + rl;
  if (n >= N_NODES) return;
  int off = slice * SCOLS + cl * 8;

  int s = row_start[n];
  int e = row_start[n + 1];
  float acc[8];
  #pragma unroll
  for (int j = 0; j < 8; ++j) acc[j] = 0.f;

  int i = s;
  for (; i + 3 < e; i += 4) {
    int c0 = csr_cols[i + 0], c1 = csr_cols[i + 1];
    int c2 = csr_cols[i + 2], c3 = csr_cols[i + 3];
    float v0 = csr_vals[i + 0], v1 = csr_vals[i + 1];
    float v2 = csr_vals[i + 2], v3 = csr_vals[i + 3];
    u16x8 p0 = *(const u16x8*)&xin[(size_t)c0 * CB + off];
    u16x8 p1 = *(const u16x8*)&xin[(size_t)c1 * CB + off];
    u16x8 p2 = *(const u16x8*)&xin[(size_t)c2 * CB + off];
    u16x8 p3 = *(const u16x8*)&xin[(size_t)c3 * CB + off];
    #pragma unroll
    for (int j = 0; j < 8; ++j) {
      acc[j] = fmaf(v0, bf2f(p0[j]), acc[j]);
      acc[j] = fmaf(v1, bf2f(p1[j]), acc[j]);
      acc[j] = fmaf(v2, bf2f(p2[j]), acc[j]);
      acc[j] = fmaf(v3, bf2f(p3[j]), acc[j]);
    }
  }
  for (; i < e; ++i) {
    int c0 = csr_cols[i];
    float v0 = csr_vals[i];
    u16x8 p0 = *(const u16x8*)&xin[(size_t)c0 * CB + off];
    #pragma unroll
    for (int j = 0; j < 8; ++j) acc[j] = fmaf(v0, bf2f(p0[j]), acc[j]);
  }

  u16x8 o;
  if (use_prev) {
    u16x8 q = *(const u16x8*)&prev[(size_t)n * CB + off];
    #pragma unroll
    for (int j = 0; j < 8; ++j) o[j] = f2bf(alpha * acc[j] - bf2f(q[j]));
  } else {
    #pragma unroll
    for (int j = 0; j < 8; ++j) o[j] = f2bf(alpha * acc[j]);
  }
  *(u16x8*)&xout[(size_t)n * CB + off] = o;
}

// ---------------- MFMA GEMM + bias + ReLU + maxpool(4) ----------------
// grid = (NPOOL, BB/MB). m = bloc*4 + nd => C/D's 4 regs per lane = pool elements (in-lane max).

template <int BB>
__global__ __launch_bounds__(256) void gemm_mfma_kernel(const unsigned short* __restrict__ slices,
                                                        const unsigned short* __restrict__ wpack,
                                                        const float* __restrict__ bias,
                                                        float* __restrict__ out, int b0) {
  constexpr int CB = 64 * BB;
  constexpr int MB = (BB >= 16) ? 16 : BB;        // b's per block
  constexpr int MT = MB / 4;                      // 16-row M-tiles
  constexpr int SPAN = MB * 64;                   // cols per block
  constexpr size_t SLICE = (size_t)N_NODES * CB;
  __shared__ unsigned short A[4 * MB * KPAD];

  int g = blockIdx.x;
  int bh = blockIdx.y;
  int t = threadIdx.x;

  constexpr int SLOTS = POLY_K * 4 * (SPAN / 8);  // ushort8 slots
  for (int idx = t; idx < SLOTS; idx += 256) {
    int kpoly = idx / (4 * (SPAN / 8));
    int r = idx % (4 * (SPAN / 8));
    int nd = r / (SPAN / 8);
    int colloc = (r % (SPAN / 8)) * 8;
    int bloc = colloc >> 6;
    int f = colloc & 63;
    u16x8 v = *(const u16x8*)&slices[(size_t)kpoly * SLICE +
                                     (size_t)(g * POOLSZ + nd) * CB + bh * SPAN + colloc];
    *(u16x8*)&A[(bloc * 4 + nd) * KPAD + kpoly * 64 + f] = v;
  }
  __syncthreads();

  int w = t >> 6;          // wave 0..3: fo-tiles {2w, 2w+1}
  int l = t & 63;
  int lm = l & 15;
  int q = l >> 4;

  f32x4 acc[MT][2];
  #pragma unroll
  for (int mt = 0; mt < MT; ++mt)
    #pragma unroll
    for (int fj = 0; fj < 2; ++fj) {
      acc[mt][fj][0] = 0.f; acc[mt][fj][1] = 0.f;
      acc[mt][fj][2] = 0.f; acc[mt][fj][3] = 0.f;
    }

  #pragma unroll
  for (int c = 0; c < 10; ++c) {
    bf16x8 bfrag[2];
    #pragma unroll
    for (int fj = 0; fj < 2; ++fj) {
      int fi = w * 2 + fj;
      bfrag[fj] = *(const bf16x8*)&wpack[(size_t)(((fi * 10) + c) * 64 + l) * 8];
    }
    #pragma unroll
    for (int mt = 0; mt < MT; ++mt) {
      bf16x8 afrag = *(const bf16x8*)&A[(mt * 16 + lm) * KPAD + c * 32 + q * 8];
      acc[mt][0] = __builtin_amdgcn_mfma_f32_16x16x32_bf16(afrag, bfrag[0], acc[mt][0], 0, 0, 0);
      acc[mt][1] = __builtin_amdgcn_mfma_f32_16x16x32_bf16(afrag, bfrag[1], acc[mt][1], 0, 0, 0);
    }
  }

  #pragma unroll
  for (int fj = 0; fj < 2; ++fj) {
    int fo = (w * 2 + fj) * 16 + lm;
    float bv = bias[fo];
    #pragma unroll
    for (int mt = 0; mt < MT; ++mt) {
      float mx = fmaxf(fmaxf(acc[mt][fj][0], acc[mt][fj][1]),
                       fmaxf(acc[mt][fj][2], acc[mt][fj][3]));
      float val = fmaxf(mx + bv, 0.f);
      int b = b0 + bh * MB + mt * 4 + q;
      out[((size_t)b * NPOOL + g) * OUT_FEAT + fo] = val;
    }
  }
}

// ---------------- pipeline ----------------

template <int BB>
static void run_pipeline(const float* x, const float* bias,
                         const int* row_start, const int* csr_cols, const float* csr_vals,
                         const unsigned short* wpack,
                         unsigned short* slices, float* out, hipStream_t stream) {
  constexpr int CB = 64 * BB;
  constexpr size_t SLICE = (size_t)N_NODES * CB;
  constexpr int LPR = (CB / 8) / 8;
  constexpr int RPB = 256 / LPR;
  constexpr int NBLK = ((N_NODES + RPB - 1) / RPB) * 8;
  constexpr int MB = (BB >= 16) ? 16 : BB;
  for (int b0 = 0; b0 < BATCH; b0 += BB) {
    transpose_kernel<BB><<<N_NODES, 256, 0, stream>>>(x, slices, b0);
    for (int k = 1; k < POLY_K; ++k) {
      const unsigned short* xin  = slices + (size_t)(k - 1) * SLICE;
      const unsigned short* prev = (k >= 2) ? slices + (size_t)(k - 2) * SLICE : slices;
      unsigned short* xout = slices + (size_t)k * SLICE;
      float alpha = (k == 1) ? 1.0f : 2.0f;
      spmm_kernel<BB><<<NBLK, 256, 0, stream>>>(xin, prev, xout, row_start,
                                                csr_cols, csr_vals, alpha,
                                                (k >= 2) ? 1 : 0);
    }
    gemm_mfma_kernel<BB><<<dim3(NPOOL, BB / MB), 256, 0, stream>>>(slices, wpack, bias, out, b0);
  }
}

static size_t needed_bytes(int BB) {
  return 1482112u + (size_t)6400000 * BB;   // CSR+wpack + 5*N*64*BB*2
}

extern "C" void kernel_launch(void* const* d_in, const int* in_sizes, int n_in,
                              void* d_out, int out_size, void* d_ws, size_t ws_size,
                              hipStream_t stream) {
  const float* x        = (const float*)d_in[0];
  const int*   lap_rows = (const int*)d_in[1];
  const int*   lap_cols = (const int*)d_in[2];
  const float* lap_vals = (const float*)d_in[3];
  const float* weight   = (const float*)d_in[4];
  const float* bias     = (const float*)d_in[5];
  float* out = (float*)d_out;

  int* deg       = (int*)d_ws;
  int* cursor    = deg + 10016;
  int* row_start = cursor + 10016;
  int* csr_cols  = row_start + 10016;
  float* csr_vals = (float*)(csr_cols + N_EDGES);
  unsigned short* wpack = (unsigned short*)(csr_vals + N_EDGES);   // 40960 ushorts
  unsigned short* slices = wpack + 40960;                          // bf16 terms

  int BB = 0;
  if      (ws_size >= needed_bytes(32)) BB = 32;   // 206.3 MB — proven fit
  else if (ws_size >= needed_bytes(16)) BB = 16;
  else if (ws_size >= needed_bytes(8))  BB = 8;
  else if (ws_size >= needed_bytes(4))  BB = 4;
  if (BB == 0) return;

  zero_int_kernel<<<(N_NODES + 255) / 256, 256, 0, stream>>>(deg, N_NODES);
  hist_kernel<<<(N_EDGES + 255) / 256, 256, 0, stream>>>(lap_rows, deg);
  scan_kernel<<<1, 1024, 0, stream>>>(deg, row_start, cursor);
  scatter_kernel<<<(N_EDGES + 255) / 256, 256, 0, stream>>>(lap_rows, lap_cols, lap_vals,
                                                            cursor, csr_cols, csr_vals);
  wpack_kernel<<<20, 256, 0, stream>>>(weight, wpack);

  switch (BB) {
    case 32: run_pipeline<32>(x, bias, row_start, csr_cols, csr_vals, wpack, slices, out, stream); break;
    case 16: run_pipeline<16>(x, bias, row_start, csr_cols, csr_vals, wpack, slices, out, stream); break;
    case 8:  run_pipeline<8>(x, bias, row_start, csr_cols, csr_vals, wpack, slices, out, stream); break;
    case 4:  run_pipeline<4>(x, bias, row_start, csr_cols, csr_vals, wpack, slices, out, stream); break;
  }
}